// Round 1
// baseline (423.554 us; speedup 1.0000x reference)
//
#include <hip/hip_runtime.h>
#include <hip/hip_bf16.h>

#define D_MODEL 1024
#define NHEAD 16
#define DH 64
#define DFF 4096
#define MAXD 32
#define L_ 2048
#define NROW 4096

typedef __attribute__((ext_vector_type(4))) float floatx4;
typedef __attribute__((ext_vector_type(8))) __bf16 bf16x8;
typedef __attribute__((ext_vector_type(4))) unsigned short ushort4v;

static __device__ inline unsigned short f2bf(float f) {
    __hip_bfloat16 h = __float2bfloat16(f);
    return __builtin_bit_cast(unsigned short, h);
}

static __device__ inline floatx4 mfma16(bf16x8 a, bf16x8 b, floatx4 c) {
    return __builtin_amdgcn_mfma_f32_16x16x32_bf16(a, b, c, 0, 0, 0);
}

// ---------------- elementwise cast fp32 -> bf16 ----------------
__global__ __launch_bounds__(256) void cast_bf16_kernel(const float* __restrict__ in,
                                                        unsigned short* __restrict__ out, int n4) {
    int i = blockIdx.x * 256 + threadIdx.x;
    if (i < n4) {
        floatx4 v = *(const floatx4*)&in[(size_t)i * 4];
        ushort4v o;
        o.x = f2bf(v[0]); o.y = f2bf(v[1]); o.z = f2bf(v[2]); o.w = f2bf(v[3]);
        *(ushort4v*)&out[(size_t)i * 4] = o;
    }
}

// ---------------- transpose + cast: W fp32 [K][N] -> WT bf16 [N][K] ----------------
__global__ __launch_bounds__(256) void transpose_cast_kernel(const float* __restrict__ W,
                                                             unsigned short* __restrict__ WT,
                                                             int K, int N) {
    __shared__ float tile[32][33];
    int k0 = blockIdx.y * 32, n0 = blockIdx.x * 32;
    for (int i = threadIdx.x; i < 1024; i += 256) {
        int r = i >> 5, c = i & 31;
        tile[r][c] = W[(size_t)(k0 + r) * N + n0 + c];
    }
    __syncthreads();
    for (int i = threadIdx.x; i < 1024; i += 256) {
        int r = i >> 5, c = i & 31;   // r: n index, c: k index
        WT[(size_t)(n0 + r) * K + k0 + c] = f2bf(tile[c][r]);
    }
}

// ---------------- pack qkv bias ----------------
__global__ __launch_bounds__(256) void pack_bias_kernel(const float* __restrict__ bq,
                                                        const float* __restrict__ bk,
                                                        const float* __restrict__ bv,
                                                        float* __restrict__ out) {
    int i = blockIdx.x * 256 + threadIdx.x;
    if (i < 3072) out[i] = (i < 1024) ? bq[i] : ((i < 2048) ? bk[i - 1024] : bv[i - 2048]);
}

// ---------------- GEMM: C[M][N] = A[M][K] @ BT[N][K]^T + bias ----------------
// 128x128 tile, 4 waves (each 64x64 = 4x4 16x16 frags), BK = 32.
template <bool OUTBF16, bool RELU>
__global__ __launch_bounds__(256) void gemm_kernel(const unsigned short* __restrict__ A,
                                                   const unsigned short* __restrict__ BT,
                                                   const float* __restrict__ bias,
                                                   void* __restrict__ Cout,
                                                   int M, int N, int K) {
    __shared__ unsigned short Asm[128][40];
    __shared__ unsigned short Bsm[128][40];
    int t = threadIdx.x;
    int lane = t & 63, w = t >> 6;
    int wm = w >> 1, wn = w & 1;
    int lr = lane & 15, hg = lane >> 4;
    int m0 = blockIdx.y * 128, n0 = blockIdx.x * 128;

    floatx4 acc[4][4];
#pragma unroll
    for (int i = 0; i < 4; i++)
#pragma unroll
        for (int j = 0; j < 4; j++) acc[i][j] = (floatx4)0.0f;

    for (int k0 = 0; k0 < K; k0 += 32) {
        __syncthreads();
#pragma unroll
        for (int i = 0; i < 2; i++) {
            int idx = t + i * 256;               // 0..511
            int r = idx >> 2, ch = idx & 3;      // 128 rows x 4 chunks(16B)
            *(int4*)&Asm[r][ch * 8] = *(const int4*)&A[(size_t)(m0 + r) * K + k0 + ch * 8];
            *(int4*)&Bsm[r][ch * 8] = *(const int4*)&BT[(size_t)(n0 + r) * K + k0 + ch * 8];
        }
        __syncthreads();
        bf16x8 af[4], bfg[4];
#pragma unroll
        for (int mf = 0; mf < 4; mf++) af[mf] = *(const bf16x8*)&Asm[wm * 64 + mf * 16 + lr][hg * 8];
#pragma unroll
        for (int nf = 0; nf < 4; nf++) bfg[nf] = *(const bf16x8*)&Bsm[wn * 64 + nf * 16 + lr][hg * 8];
#pragma unroll
        for (int mf = 0; mf < 4; mf++)
#pragma unroll
            for (int nf = 0; nf < 4; nf++) acc[mf][nf] = mfma16(af[mf], bfg[nf], acc[mf][nf]);
    }

#pragma unroll
    for (int mf = 0; mf < 4; mf++)
#pragma unroll
        for (int nf = 0; nf < 4; nf++) {
            int col = n0 + wn * 64 + nf * 16 + lr;
            float bv = bias[col];
#pragma unroll
            for (int r = 0; r < 4; r++) {
                int row = m0 + wm * 64 + mf * 16 + hg * 4 + r;
                float v = acc[mf][nf][r] + bv;
                if (RELU) v = v > 0.f ? v : 0.f;
                if (OUTBF16)
                    ((unsigned short*)Cout)[(size_t)row * N + col] = f2bf(v);
                else
                    ((float*)Cout)[(size_t)row * N + col] = v;
            }
        }
}

// ---------------- fused attention with RPE bias ----------------
// grid: (b*16+h)*16+qb, 512 blocks, 256 threads (4 waves x 32 q-rows = 128 q rows/block)
__global__ __launch_bounds__(256) void attn_kernel(const unsigned short* __restrict__ qkv, // [4096][3072]
                                                   const float* __restrict__ rpe,          // [65][16]
                                                   unsigned short* __restrict__ ctx) {     // [4096][1024]
    __shared__ unsigned short Qs[128][72];
    __shared__ unsigned short Ks[64][72];
    __shared__ unsigned short Vt[64][72];   // transposed: [d][key]
    __shared__ unsigned short Ps[4][32][72];
    __shared__ float rpl[65];

    int t = threadIdx.x;
    int lane = t & 63, w = t >> 6;
    int lr = lane & 15, hg = lane >> 4;

    int blk = blockIdx.x;
    int qb = blk & 15;
    int h = (blk >> 4) & 15;
    int b = blk >> 8;
    int q0 = qb * 128;
    size_t rowbase = (size_t)b * L_ * 3072;

    if (t < 65) rpl[t] = rpe[t * NHEAD + h];

    // stage Q: 128 rows x 64 cols
#pragma unroll
    for (int i = 0; i < 4; i++) {
        int idx = t + i * 256;
        int r = idx >> 3, ch = idx & 7;
        *(int4*)&Qs[r][ch * 8] = *(const int4*)&qkv[rowbase + (size_t)(q0 + r) * 3072 + h * 64 + ch * 8];
    }
    __syncthreads();

    bf16x8 qf[2][2];
#pragma unroll
    for (int mf = 0; mf < 2; mf++)
#pragma unroll
        for (int kc = 0; kc < 2; kc++)
            qf[mf][kc] = *(const bf16x8*)&Qs[w * 32 + mf * 16 + lr][kc * 32 + hg * 8];

    floatx4 o[2][4];
#pragma unroll
    for (int mf = 0; mf < 2; mf++)
#pragma unroll
        for (int nf = 0; nf < 4; nf++) o[mf][nf] = (floatx4)0.f;
    float mstate[2][4], lstate[2][4];
#pragma unroll
    for (int mf = 0; mf < 2; mf++)
#pragma unroll
        for (int r = 0; r < 4; r++) { mstate[mf][r] = -1e30f; lstate[mf][r] = 0.f; }

    const float scale = 0.125f;

    for (int kt = 0; kt < L_ / 64; kt++) {
        int key0 = kt * 64;
        __syncthreads();   // protect K/V LDS from previous iteration's readers
        // stage K tile [64][64]
#pragma unroll
        for (int i = 0; i < 2; i++) {
            int idx = t + i * 256;
            int r = idx >> 3, ch = idx & 7;
            *(int4*)&Ks[r][ch * 8] =
                *(const int4*)&qkv[rowbase + (size_t)(key0 + r) * 3072 + 1024 + h * 64 + ch * 8];
        }
        // stage V transposed: Vt[d][key]
#pragma unroll
        for (int i = 0; i < 2; i++) {
            int idx = t + i * 256;
            int r = idx >> 3, ch = idx & 7;
            union { int4 v; unsigned short u[8]; } tmp;
            tmp.v = *(const int4*)&qkv[rowbase + (size_t)(key0 + r) * 3072 + 2048 + h * 64 + ch * 8];
#pragma unroll
            for (int e = 0; e < 8; e++) Vt[ch * 8 + e][r] = tmp.u[e];
        }
        __syncthreads();

        // S = Q K^T  (per wave: 2 m-frags x 4 n-frags, Kdim=64 -> 2 chained MFMAs)
        floatx4 s[2][4];
#pragma unroll
        for (int mf = 0; mf < 2; mf++)
#pragma unroll
            for (int nf = 0; nf < 4; nf++) {
                floatx4 a = (floatx4)0.f;
#pragma unroll
                for (int kc = 0; kc < 2; kc++) {
                    bf16x8 kf = *(const bf16x8*)&Ks[nf * 16 + lr][kc * 32 + hg * 8];
                    a = mfma16(qf[mf][kc], kf, a);
                }
                s[mf][nf] = a;
            }

        // online softmax update + write P to LDS (bf16)
#pragma unroll
        for (int mf = 0; mf < 2; mf++) {
#pragma unroll
            for (int r = 0; r < 4; r++) {
                int qi = q0 + w * 32 + mf * 16 + hg * 4 + r;
                float mx = -1e30f;
                float sv[4];
#pragma unroll
                for (int nf = 0; nf < 4; nf++) {
                    int kj = key0 + nf * 16 + lr;
                    int rel = kj - qi;
                    rel = rel < -MAXD ? -MAXD : (rel > MAXD ? MAXD : rel);
                    float v = s[mf][nf][r] * scale + rpl[rel + MAXD];
                    sv[nf] = v;
                    mx = fmaxf(mx, v);
                }
#pragma unroll
                for (int d = 1; d < 16; d <<= 1) mx = fmaxf(mx, __shfl_xor(mx, d, 64));
                float newm = fmaxf(mstate[mf][r], mx);
                float corr = __expf(mstate[mf][r] - newm);
                float rs = 0.f;
#pragma unroll
                for (int nf = 0; nf < 4; nf++) {
                    float p = __expf(sv[nf] - newm);
                    rs += p;
                    Ps[w][mf * 16 + hg * 4 + r][nf * 16 + lr] = f2bf(p);
                }
#pragma unroll
                for (int d = 1; d < 16; d <<= 1) rs += __shfl_xor(rs, d, 64);
                lstate[mf][r] = lstate[mf][r] * corr + rs;
                mstate[mf][r] = newm;
#pragma unroll
                for (int nf = 0; nf < 4; nf++) o[mf][nf][r] = o[mf][nf][r] * corr;
            }
        }
        __syncthreads();   // P writes complete

        // O += P @ V
        bf16x8 vf[4][2];
#pragma unroll
        for (int nf = 0; nf < 4; nf++)
#pragma unroll
            for (int hf = 0; hf < 2; hf++)
                vf[nf][hf] = *(const bf16x8*)&Vt[nf * 16 + lr][hf * 32 + hg * 8];
#pragma unroll
        for (int mf = 0; mf < 2; mf++) {
            bf16x8 pf[2];
#pragma unroll
            for (int hf = 0; hf < 2; hf++)
                pf[hf] = *(const bf16x8*)&Ps[w][mf * 16 + lr][hf * 32 + hg * 8];
#pragma unroll
            for (int nf = 0; nf < 4; nf++)
#pragma unroll
                for (int hf = 0; hf < 2; hf++) o[mf][nf] = mfma16(pf[hf], vf[nf][hf], o[mf][nf]);
        }
    }

    // normalize + write ctx (bf16)
#pragma unroll
    for (int mf = 0; mf < 2; mf++)
#pragma unroll
        for (int r = 0; r < 4; r++) {
            float inv = 1.f / lstate[mf][r];
            int row = b * L_ + q0 + w * 32 + mf * 16 + hg * 4 + r;
#pragma unroll
            for (int nf = 0; nf < 4; nf++)
                ctx[(size_t)row * 1024 + h * 64 + nf * 16 + lr] = f2bf(o[mf][nf][r] * inv);
        }
}

// ---------------- fused residual + layernorm ----------------
template <bool WBF>
__global__ __launch_bounds__(256) void resln_kernel(const float* __restrict__ ra,
                                                    const float* __restrict__ rb,
                                                    const float* __restrict__ g,
                                                    const float* __restrict__ be,
                                                    float* __restrict__ outf,
                                                    unsigned short* __restrict__ outb) {
    __shared__ float red[4];
    __shared__ float red2[4];
    int row = blockIdx.x;
    int t = threadIdx.x;
    int w = t >> 6, lane = t & 63;
    size_t base = (size_t)row * 1024 + t * 4;
    floatx4 a = *(const floatx4*)&ra[base];
    floatx4 b = *(const floatx4*)&rb[base];
    floatx4 y = a + b;
    float s = y[0] + y[1] + y[2] + y[3];
#pragma unroll
    for (int d = 1; d < 64; d <<= 1) s += __shfl_xor(s, d, 64);
    if (lane == 0) red[w] = s;
    __syncthreads();
    float mu = (red[0] + red[1] + red[2] + red[3]) * (1.f / 1024.f);
    floatx4 d4 = y - mu;
    float sq = d4[0] * d4[0] + d4[1] * d4[1] + d4[2] * d4[2] + d4[3] * d4[3];
#pragma unroll
    for (int d = 1; d < 64; d <<= 1) sq += __shfl_xor(sq, d, 64);
    if (lane == 0) red2[w] = sq;
    __syncthreads();
    float var = (red2[0] + red2[1] + red2[2] + red2[3]) * (1.f / 1024.f);
    float rstd = rsqrtf(var + 1e-5f);
    floatx4 gg = *(const floatx4*)&g[t * 4];
    floatx4 bb = *(const floatx4*)&be[t * 4];
    floatx4 outv;
#pragma unroll
    for (int i = 0; i < 4; i++) outv[i] = d4[i] * rstd * gg[i] + bb[i];
    *(floatx4*)&outf[base] = outv;
    if (WBF) {
        ushort4v ov;
        ov.x = f2bf(outv[0]); ov.y = f2bf(outv[1]); ov.z = f2bf(outv[2]); ov.w = f2bf(outv[3]);
        *(ushort4v*)&outb[base] = ov;
    }
}

extern "C" void kernel_launch(void* const* d_in, const int* in_sizes, int n_in,
                              void* d_out, int out_size, void* d_ws, size_t ws_size,
                              hipStream_t stream) {
    const float* src = (const float*)d_in[0];
    const float* Wq = (const float*)d_in[1];
    const float* Wk = (const float*)d_in[2];
    const float* Wv = (const float*)d_in[3];
    const float* bq = (const float*)d_in[4];
    const float* bk = (const float*)d_in[5];
    const float* bv = (const float*)d_in[6];
    const float* Wo = (const float*)d_in[7];
    const float* bo = (const float*)d_in[8];
    const float* rpe = (const float*)d_in[9];
    const float* W1 = (const float*)d_in[10];
    const float* b1 = (const float*)d_in[11];
    const float* W2 = (const float*)d_in[12];
    const float* b2 = (const float*)d_in[13];
    const float* ln1g = (const float*)d_in[14];
    const float* ln1b = (const float*)d_in[15];
    const float* ln2g = (const float*)d_in[16];
    const float* ln2b = (const float*)d_in[17];
    float* out = (float*)d_out;
    char* ws = (char*)d_ws;

    // workspace layout (bytes)
    const size_t o_srcb = 0;                       // 8 MB   bf16 src; later reused as xb
    const size_t o_wtqkv = o_srcb + 8388608;       // 6 MB   WT_qkv [3072][1024]
    const size_t o_wto = o_wtqkv + 6291456;        // 2 MB   WT_o  [1024][1024]
    const size_t o_wt1 = o_wto + 2097152;          // 8 MB   WT_1  [4096][1024]
    const size_t o_wt2 = o_wt1 + 8388608;          // 8 MB   WT_2  [1024][4096]
    const size_t o_bqkv = o_wt2 + 8388608;         // 12 KB
    const size_t o_qkv = o_bqkv + 12288;           // 24 MB  qkv bf16; later reused as attnout/ff fp32
    const size_t o_ctxb = o_qkv + 25165824;        // 8 MB   ctx bf16
    const size_t o_x = o_ctxb + 8388608;           // 16 MB  x fp32
    const size_t o_hb = o_x + 16777216;            // 32 MB  hidden bf16 [4096][4096]

    unsigned short* srcb = (unsigned short*)(ws + o_srcb);
    unsigned short* wtqkv = (unsigned short*)(ws + o_wtqkv);
    unsigned short* wto = (unsigned short*)(ws + o_wto);
    unsigned short* wt1 = (unsigned short*)(ws + o_wt1);
    unsigned short* wt2 = (unsigned short*)(ws + o_wt2);
    float* bqkv = (float*)(ws + o_bqkv);
    unsigned short* qkvb = (unsigned short*)(ws + o_qkv);
    unsigned short* ctxb = (unsigned short*)(ws + o_ctxb);
    float* x = (float*)(ws + o_x);
    unsigned short* hb = (unsigned short*)(ws + o_hb);
    float* attnout = (float*)(ws + o_qkv);   // alias: qkv dead after attention
    float* ff = (float*)(ws + o_qkv);        // alias: attnout dead after LN1
    unsigned short* xb = (unsigned short*)(ws + o_srcb);  // alias: srcb dead after QKV gemm

    // 1. casts
    cast_bf16_kernel<<<4096, 256, 0, stream>>>(src, srcb, 1048576);
    transpose_cast_kernel<<<dim3(32, 32), 256, 0, stream>>>(Wq, wtqkv, 1024, 1024);
    transpose_cast_kernel<<<dim3(32, 32), 256, 0, stream>>>(Wk, wtqkv + 1024 * 1024, 1024, 1024);
    transpose_cast_kernel<<<dim3(32, 32), 256, 0, stream>>>(Wv, wtqkv + 2 * 1024 * 1024, 1024, 1024);
    transpose_cast_kernel<<<dim3(32, 32), 256, 0, stream>>>(Wo, wto, 1024, 1024);
    transpose_cast_kernel<<<dim3(128, 32), 256, 0, stream>>>(W1, wt1, 1024, 4096);
    transpose_cast_kernel<<<dim3(32, 128), 256, 0, stream>>>(W2, wt2, 4096, 1024);
    pack_bias_kernel<<<12, 256, 0, stream>>>(bq, bk, bv, bqkv);

    // 2. fused QKV projection: [4096][3072]
    gemm_kernel<true, false><<<dim3(24, 32), 256, 0, stream>>>(srcb, wtqkv, bqkv, qkvb, NROW, 3072, 1024);

    // 3. attention -> ctx bf16
    attn_kernel<<<512, 256, 0, stream>>>(qkvb, rpe, ctxb);

    // 4. output projection -> attnout fp32
    gemm_kernel<false, false><<<dim3(8, 32), 256, 0, stream>>>(ctxb, wto, bo, attnout, NROW, 1024, 1024);

    // 5. x = LN1(src + attnout), also bf16 copy
    resln_kernel<true><<<4096, 256, 0, stream>>>(src, attnout, ln1g, ln1b, x, xb);

    // 6. FFN gemm1 + relu -> hb bf16 [4096][4096]
    gemm_kernel<true, true><<<dim3(32, 32), 256, 0, stream>>>(xb, wt1, b1, hb, NROW, 4096, 1024);

    // 7. FFN gemm2 -> ff fp32
    gemm_kernel<false, false><<<dim3(8, 32), 256, 0, stream>>>(hb, wt2, b2, ff, NROW, 1024, 4096);

    // 8. out = LN2(x + ff)
    resln_kernel<false><<<4096, 256, 0, stream>>>(x, ff, ln2g, ln2b, out, nullptr);
}

// Round 2
// 413.323 us; speedup vs baseline: 1.0248x; 1.0248x over previous
//
#include <hip/hip_runtime.h>
#include <hip/hip_bf16.h>

#define D_MODEL 1024
#define NHEAD 16
#define DH 64
#define DFF 4096
#define MAXD 32
#define L_ 2048
#define NROW 4096

typedef __attribute__((ext_vector_type(4))) float floatx4;
typedef __attribute__((ext_vector_type(8))) __bf16 bf16x8;
typedef __attribute__((ext_vector_type(4))) unsigned short ushort4v;

static __device__ inline unsigned short f2bf(float f) {
    __hip_bfloat16 h = __float2bfloat16(f);
    return __builtin_bit_cast(unsigned short, h);
}

static __device__ inline floatx4 mfma16(bf16x8 a, bf16x8 b, floatx4 c) {
    return __builtin_amdgcn_mfma_f32_16x16x32_bf16(a, b, c, 0, 0, 0);
}

static __device__ inline void gload_lds16(const unsigned short* g, unsigned short* l) {
    __builtin_amdgcn_global_load_lds((const __attribute__((address_space(1))) unsigned int*)g,
                                     (__attribute__((address_space(3))) unsigned int*)l,
                                     16, 0, 0);
}

// ---------------- elementwise cast fp32 -> bf16 ----------------
__global__ __launch_bounds__(256) void cast_bf16_kernel(const float* __restrict__ in,
                                                        unsigned short* __restrict__ out, int n4) {
    int i = blockIdx.x * 256 + threadIdx.x;
    if (i < n4) {
        floatx4 v = *(const floatx4*)&in[(size_t)i * 4];
        ushort4v o;
        o.x = f2bf(v[0]); o.y = f2bf(v[1]); o.z = f2bf(v[2]); o.w = f2bf(v[3]);
        *(ushort4v*)&out[(size_t)i * 4] = o;
    }
}

// ---------------- transpose + cast: W fp32 [K][N] -> WT bf16 [N][K] ----------------
__global__ __launch_bounds__(256) void transpose_cast_kernel(const float* __restrict__ W,
                                                             unsigned short* __restrict__ WT,
                                                             int K, int N) {
    __shared__ float tile[32][33];
    int k0 = blockIdx.y * 32, n0 = blockIdx.x * 32;
    for (int i = threadIdx.x; i < 1024; i += 256) {
        int r = i >> 5, c = i & 31;
        tile[r][c] = W[(size_t)(k0 + r) * N + n0 + c];
    }
    __syncthreads();
    for (int i = threadIdx.x; i < 1024; i += 256) {
        int r = i >> 5, c = i & 31;
        WT[(size_t)(n0 + r) * K + k0 + c] = f2bf(tile[c][r]);
    }
}

// ---------------- pack qkv bias ----------------
__global__ __launch_bounds__(256) void pack_bias_kernel(const float* __restrict__ bq,
                                                        const float* __restrict__ bk,
                                                        const float* __restrict__ bv,
                                                        float* __restrict__ out) {
    int i = blockIdx.x * 256 + threadIdx.x;
    if (i < 3072) out[i] = (i < 1024) ? bq[i] : ((i < 2048) ? bk[i - 1024] : bv[i - 2048]);
}

// ---------------- GEMM: C[M][N] = A[M][K] @ BT[N][K]^T + bias ----------------
// m97 structure: 128x128 tile, 4 waves, BK=32, global_load_lds width-16 staging, linear LDS.
template <bool OUTBF16, bool RELU>
__global__ __launch_bounds__(256) void gemm_kernel(const unsigned short* __restrict__ A,
                                                   const unsigned short* __restrict__ BT,
                                                   const float* __restrict__ bias,
                                                   void* __restrict__ Cout,
                                                   int M, int N, int K) {
    __shared__ unsigned short Asm[128][32];
    __shared__ unsigned short Bsm[128][32];
    int t = threadIdx.x;
    int lane = t & 63, w = t >> 6;
    int wm = w >> 1, wn = w & 1;
    int lr = lane & 15, hg = lane >> 4;
    int m0 = blockIdx.y * 128, n0 = blockIdx.x * 128;

    floatx4 acc[4][4];
#pragma unroll
    for (int i = 0; i < 4; i++)
#pragma unroll
        for (int j = 0; j < 4; j++) acc[i][j] = (floatx4)0.0f;

    int r0 = t >> 2, c0 = (t & 3) * 8;
    int r1 = (t + 256) >> 2, c1 = ((t + 256) & 3) * 8;

    for (int k0 = 0; k0 < K; k0 += 32) {
        __syncthreads();
        gload_lds16(&A[(size_t)(m0 + r0) * K + k0 + c0], &Asm[r0][c0]);
        gload_lds16(&A[(size_t)(m0 + r1) * K + k0 + c1], &Asm[r1][c1]);
        gload_lds16(&BT[(size_t)(n0 + r0) * K + k0 + c0], &Bsm[r0][c0]);
        gload_lds16(&BT[(size_t)(n0 + r1) * K + k0 + c1], &Bsm[r1][c1]);
        __syncthreads();
        bf16x8 af[4], bfg[4];
#pragma unroll
        for (int mf = 0; mf < 4; mf++) af[mf] = *(const bf16x8*)&Asm[wm * 64 + mf * 16 + lr][hg * 8];
#pragma unroll
        for (int nf = 0; nf < 4; nf++) bfg[nf] = *(const bf16x8*)&Bsm[wn * 64 + nf * 16 + lr][hg * 8];
#pragma unroll
        for (int mf = 0; mf < 4; mf++)
#pragma unroll
            for (int nf = 0; nf < 4; nf++) acc[mf][nf] = mfma16(af[mf], bfg[nf], acc[mf][nf]);
    }

#pragma unroll
    for (int mf = 0; mf < 4; mf++)
#pragma unroll
        for (int nf = 0; nf < 4; nf++) {
            int col = n0 + wn * 64 + nf * 16 + lr;
            float bv = bias[col];
#pragma unroll
            for (int r = 0; r < 4; r++) {
                int row = m0 + wm * 64 + mf * 16 + hg * 4 + r;
                float v = acc[mf][nf][r] + bv;
                if (RELU) v = v > 0.f ? v : 0.f;
                if (OUTBF16)
                    ((unsigned short*)Cout)[(size_t)row * N + col] = f2bf(v);
                else
                    ((float*)Cout)[(size_t)row * N + col] = v;
            }
        }
}

// ---------------- fused attention with RPE bias ----------------
// 512 blocks x 512 threads. 8 waves x 16 q-rows = 128 q rows/block. KV tile = 64.
__global__ __launch_bounds__(512, 4) void attn_kernel(const unsigned short* __restrict__ qkv, // [4096][3072]
                                                      const float* __restrict__ rpe,          // [65][16]
                                                      unsigned short* __restrict__ ctx) {     // [4096][1024]
    __shared__ unsigned short QP[128][68];     // Q staging, then P tiles (Q dead after frag load)
    __shared__ unsigned short Kb[2][64][68];   // double-buffered K
    __shared__ unsigned short Vt[64][68];      // transposed V: [d][key]
    __shared__ float rpl[65];

    int t = threadIdx.x;
    int lane = t & 63, w = t >> 6;
    int lr = lane & 15, hg = lane >> 4;

    int blk = blockIdx.x;
    int qb = blk & 15;
    int h = (blk >> 4) & 15;
    int b = blk >> 8;
    int q0 = qb * 128;
    size_t rowbase = (size_t)b * L_ * 3072;

    if (t < 65) rpl[t] = rpe[t * NHEAD + h];

    // stage Q: 128 rows x 64 cols = 1024 16B chunks, 2 per thread
    {
        int idx = t, r = idx >> 3, ch = idx & 7;
        *(int4*)&QP[r][ch * 8] = *(const int4*)&qkv[rowbase + (size_t)(q0 + r) * 3072 + h * 64 + ch * 8];
        idx = t + 512; r = idx >> 3; ch = idx & 7;
        *(int4*)&QP[r][ch * 8] = *(const int4*)&qkv[rowbase + (size_t)(q0 + r) * 3072 + h * 64 + ch * 8];
    }
    // stage K tile 0
    int kr = t >> 3, kch = t & 7;
    *(int4*)&Kb[0][kr][kch * 8] = *(const int4*)&qkv[rowbase + (size_t)kr * 3072 + 1024 + h * 64 + kch * 8];
    __syncthreads();

    bf16x8 qf[2];
    qf[0] = *(const bf16x8*)&QP[w * 16 + lr][hg * 8];
    qf[1] = *(const bf16x8*)&QP[w * 16 + lr][32 + hg * 8];
    float rpl0 = rpl[0], rpl64 = rpl[64];

    floatx4 o[4];
#pragma unroll
    for (int nf = 0; nf < 4; nf++) o[nf] = (floatx4)0.f;
    float mst[4], lst[4];
#pragma unroll
    for (int r = 0; r < 4; r++) { mst[r] = -1e30f; lst[r] = 0.f; }

    const float scale = 0.125f;

    for (int kt = 0; kt < L_ / 64; kt++) {
        int key0 = kt * 64;
        __syncthreads();   // sync1: prev PV done (Vt/QP reusable), K[kt] staged & visible

        // issue V load early (consumed after softmax)
        union { int4 v; unsigned short u[8]; } tv;
        tv.v = *(const int4*)&qkv[rowbase + (size_t)(key0 + kr) * 3072 + 2048 + h * 64 + kch * 8];
        // stage next K tile into other buffer
        if (kt + 1 < L_ / 64) {
            *(int4*)&Kb[(kt + 1) & 1][kr][kch * 8] =
                *(const int4*)&qkv[rowbase + (size_t)(key0 + 64 + kr) * 3072 + 1024 + h * 64 + kch * 8];
        }

        // S = Q K^T
        int cur = kt & 1;
        floatx4 s[4];
#pragma unroll
        for (int nf = 0; nf < 4; nf++) {
            floatx4 a = (floatx4)0.f;
            a = mfma16(qf[0], *(const bf16x8*)&Kb[cur][nf * 16 + lr][hg * 8], a);
            a = mfma16(qf[1], *(const bf16x8*)&Kb[cur][nf * 16 + lr][32 + hg * 8], a);
            s[nf] = a;
        }

        // constant-bias fast path when tile fully outside the +/-32 band
        bool rightC = (key0 > q0 + 159);
        bool leftC = (key0 + 95 < q0);
        bool cc = leftC || rightC;
        float cb = rightC ? rpl64 : rpl0;

        // online softmax, rows hg*4+r
#pragma unroll
        for (int r = 0; r < 4; r++) {
            float sv[4];
            float mx = -1e30f;
            if (cc) {
#pragma unroll
                for (int nf = 0; nf < 4; nf++) {
                    float v = s[nf][r] * scale + cb;
                    sv[nf] = v;
                    mx = fmaxf(mx, v);
                }
            } else {
                int qi = q0 + w * 16 + hg * 4 + r;
#pragma unroll
                for (int nf = 0; nf < 4; nf++) {
                    int rel = key0 + nf * 16 + lr - qi;
                    rel = rel < -MAXD ? -MAXD : (rel > MAXD ? MAXD : rel);
                    float v = s[nf][r] * scale + rpl[rel + MAXD];
                    sv[nf] = v;
                    mx = fmaxf(mx, v);
                }
            }
#pragma unroll
            for (int d = 1; d < 16; d <<= 1) mx = fmaxf(mx, __shfl_xor(mx, d, 64));
            float newm = fmaxf(mst[r], mx);
            float corr = __expf(mst[r] - newm);
            float rs = 0.f;
#pragma unroll
            for (int nf = 0; nf < 4; nf++) {
                float p = __expf(sv[nf] - newm);
                rs += p;
                QP[w * 16 + hg * 4 + r][nf * 16 + lr] = f2bf(p);
            }
#pragma unroll
            for (int d = 1; d < 16; d <<= 1) rs += __shfl_xor(rs, d, 64);
            lst[r] = lst[r] * corr + rs;
            mst[r] = newm;
#pragma unroll
            for (int nf = 0; nf < 4; nf++) o[nf][r] = o[nf][r] * corr;
        }

        // transpose-write V to LDS, e-rotated so the 8 ch-lanes hit distinct banks
#pragma unroll
        for (int j = 0; j < 8; j++) {
            int e = (kch + j) & 7;
            Vt[kch * 8 + e][kr] = tv.u[e];
        }
        __syncthreads();   // sync2: P + Vt visible

        // O += P @ V
#pragma unroll
        for (int nf = 0; nf < 4; nf++) {
            bf16x8 pf0 = *(const bf16x8*)&QP[w * 16 + lr][hg * 8];
            bf16x8 pf1 = *(const bf16x8*)&QP[w * 16 + lr][32 + hg * 8];
            bf16x8 vf0 = *(const bf16x8*)&Vt[nf * 16 + lr][hg * 8];
            bf16x8 vf1 = *(const bf16x8*)&Vt[nf * 16 + lr][32 + hg * 8];
            o[nf] = mfma16(pf0, vf0, o[nf]);
            o[nf] = mfma16(pf1, vf1, o[nf]);
        }
    }

    // normalize + write ctx (bf16)
#pragma unroll
    for (int r = 0; r < 4; r++) {
        float inv = 1.f / lst[r];
        int row = b * L_ + q0 + w * 16 + hg * 4 + r;
#pragma unroll
        for (int nf = 0; nf < 4; nf++)
            ctx[(size_t)row * 1024 + h * 64 + nf * 16 + lr] = f2bf(o[nf][r] * inv);
    }
}

// ---------------- fused residual + layernorm ----------------
template <bool WBF>
__global__ __launch_bounds__(256) void resln_kernel(const float* __restrict__ ra,
                                                    const float* __restrict__ rb,
                                                    const float* __restrict__ g,
                                                    const float* __restrict__ be,
                                                    float* __restrict__ outf,
                                                    unsigned short* __restrict__ outb) {
    __shared__ float red[4];
    __shared__ float red2[4];
    int row = blockIdx.x;
    int t = threadIdx.x;
    int w = t >> 6, lane = t & 63;
    size_t base = (size_t)row * 1024 + t * 4;
    floatx4 a = *(const floatx4*)&ra[base];
    floatx4 b = *(const floatx4*)&rb[base];
    floatx4 y = a + b;
    float s = y[0] + y[1] + y[2] + y[3];
#pragma unroll
    for (int d = 1; d < 64; d <<= 1) s += __shfl_xor(s, d, 64);
    if (lane == 0) red[w] = s;
    __syncthreads();
    float mu = (red[0] + red[1] + red[2] + red[3]) * (1.f / 1024.f);
    floatx4 d4 = y - mu;
    float sq = d4[0] * d4[0] + d4[1] * d4[1] + d4[2] * d4[2] + d4[3] * d4[3];
#pragma unroll
    for (int d = 1; d < 64; d <<= 1) sq += __shfl_xor(sq, d, 64);
    if (lane == 0) red2[w] = sq;
    __syncthreads();
    float var = (red2[0] + red2[1] + red2[2] + red2[3]) * (1.f / 1024.f);
    float rstd = rsqrtf(var + 1e-5f);
    floatx4 gg = *(const floatx4*)&g[t * 4];
    floatx4 bb = *(const floatx4*)&be[t * 4];
    floatx4 outv;
#pragma unroll
    for (int i = 0; i < 4; i++) outv[i] = d4[i] * rstd * gg[i] + bb[i];
    *(floatx4*)&outf[base] = outv;
    if (WBF) {
        ushort4v ov;
        ov.x = f2bf(outv[0]); ov.y = f2bf(outv[1]); ov.z = f2bf(outv[2]); ov.w = f2bf(outv[3]);
        *(ushort4v*)&outb[base] = ov;
    }
}

extern "C" void kernel_launch(void* const* d_in, const int* in_sizes, int n_in,
                              void* d_out, int out_size, void* d_ws, size_t ws_size,
                              hipStream_t stream) {
    const float* src = (const float*)d_in[0];
    const float* Wq = (const float*)d_in[1];
    const float* Wk = (const float*)d_in[2];
    const float* Wv = (const float*)d_in[3];
    const float* bq = (const float*)d_in[4];
    const float* bk = (const float*)d_in[5];
    const float* bv = (const float*)d_in[6];
    const float* Wo = (const float*)d_in[7];
    const float* bo = (const float*)d_in[8];
    const float* rpe = (const float*)d_in[9];
    const float* W1 = (const float*)d_in[10];
    const float* b1 = (const float*)d_in[11];
    const float* W2 = (const float*)d_in[12];
    const float* b2 = (const float*)d_in[13];
    const float* ln1g = (const float*)d_in[14];
    const float* ln1b = (const float*)d_in[15];
    const float* ln2g = (const float*)d_in[16];
    const float* ln2b = (const float*)d_in[17];
    float* out = (float*)d_out;
    char* ws = (char*)d_ws;

    const size_t o_srcb = 0;                       // 8 MB   bf16 src; later reused as xb
    const size_t o_wtqkv = o_srcb + 8388608;       // 6 MB
    const size_t o_wto = o_wtqkv + 6291456;        // 2 MB
    const size_t o_wt1 = o_wto + 2097152;          // 8 MB
    const size_t o_wt2 = o_wt1 + 8388608;          // 8 MB
    const size_t o_bqkv = o_wt2 + 8388608;         // 12 KB
    const size_t o_qkv = o_bqkv + 12288;           // 24 MB  qkv bf16; later reused as attnout/ff fp32
    const size_t o_ctxb = o_qkv + 25165824;        // 8 MB
    const size_t o_x = o_ctxb + 8388608;           // 16 MB
    const size_t o_hb = o_x + 16777216;            // 32 MB

    unsigned short* srcb = (unsigned short*)(ws + o_srcb);
    unsigned short* wtqkv = (unsigned short*)(ws + o_wtqkv);
    unsigned short* wto = (unsigned short*)(ws + o_wto);
    unsigned short* wt1 = (unsigned short*)(ws + o_wt1);
    unsigned short* wt2 = (unsigned short*)(ws + o_wt2);
    float* bqkv = (float*)(ws + o_bqkv);
    unsigned short* qkvb = (unsigned short*)(ws + o_qkv);
    unsigned short* ctxb = (unsigned short*)(ws + o_ctxb);
    float* x = (float*)(ws + o_x);
    unsigned short* hb = (unsigned short*)(ws + o_hb);
    float* attnout = (float*)(ws + o_qkv);
    float* ff = (float*)(ws + o_qkv);
    unsigned short* xb = (unsigned short*)(ws + o_srcb);

    cast_bf16_kernel<<<4096, 256, 0, stream>>>(src, srcb, 1048576);
    transpose_cast_kernel<<<dim3(32, 32), 256, 0, stream>>>(Wq, wtqkv, 1024, 1024);
    transpose_cast_kernel<<<dim3(32, 32), 256, 0, stream>>>(Wk, wtqkv + 1024 * 1024, 1024, 1024);
    transpose_cast_kernel<<<dim3(32, 32), 256, 0, stream>>>(Wv, wtqkv + 2 * 1024 * 1024, 1024, 1024);
    transpose_cast_kernel<<<dim3(32, 32), 256, 0, stream>>>(Wo, wto, 1024, 1024);
    transpose_cast_kernel<<<dim3(128, 32), 256, 0, stream>>>(W1, wt1, 1024, 4096);
    transpose_cast_kernel<<<dim3(32, 128), 256, 0, stream>>>(W2, wt2, 4096, 1024);
    pack_bias_kernel<<<12, 256, 0, stream>>>(bq, bk, bv, bqkv);

    gemm_kernel<true, false><<<dim3(24, 32), 256, 0, stream>>>(srcb, wtqkv, bqkv, qkvb, NROW, 3072, 1024);
    attn_kernel<<<512, 512, 0, stream>>>(qkvb, rpe, ctxb);
    gemm_kernel<false, false><<<dim3(8, 32), 256, 0, stream>>>(ctxb, wto, bo, attnout, NROW, 1024, 1024);
    resln_kernel<true><<<4096, 256, 0, stream>>>(src, attnout, ln1g, ln1b, x, xb);
    gemm_kernel<true, true><<<dim3(32, 32), 256, 0, stream>>>(xb, wt1, b1, hb, NROW, 4096, 1024);
    gemm_kernel<false, false><<<dim3(8, 32), 256, 0, stream>>>(hb, wt2, b2, ff, NROW, 1024, 4096);
    resln_kernel<false><<<4096, 256, 0, stream>>>(x, ff, ln2g, ln2b, out, nullptr);
}